// Round 8
// baseline (206.308 us; speedup 1.0000x reference)
//
#include <hip/hip_runtime.h>
#include <hip/hip_bf16.h>

#define S_LEN 8192
#define D_DIM 128
#define WIN   256
#define QT    128
#define KVB   64
#define NITER 10            // (QT + 2*WIN) / KVB
#define VSTRIDE 144         // bytes per Vt row (72 bf16 elems)

typedef __attribute__((ext_vector_type(8))) short bf16x8;
typedef __attribute__((ext_vector_type(4))) float f32x4;

__device__ inline unsigned pack2(float lo, float hi) {
    __hip_bfloat162 h = __float22bfloat162_rn(make_float2(lo, hi));  // v_cvt_pk_bf16_f32
    unsigned r; __builtin_memcpy(&r, &h, 4); return r;
}

__global__ __launch_bounds__(512)
void swa_fwd(const float* __restrict__ Qg, const float* __restrict__ Kg,
             const float* __restrict__ Vg, float* __restrict__ Og) {
    // K tile: row-major [64][128] bf16, XOR-swizzled (byte ^= (row&7)<<4)
    __shared__ __align__(16) unsigned short Klds[KVB * D_DIM];
    // V^T tile: [d=128][k=64] bf16, row stride 72 elems (144 B) -> conflict-free phases
    __shared__ __align__(16) unsigned short Vt[D_DIM * (VSTRIDE / 2)];

    const int tid = threadIdx.x;
    const int l = tid & 63;
    const int w = tid >> 6;        // wave 0..7, each owns 16 q-rows
    const int q = l & 15;
    const int g = l >> 4;
    const int h = blockIdx.y;
    const int q0 = blockIdx.x * QT;
    const float scale = 0.08838834764831845f;  // 1/sqrt(128)

    const float* Qh = Qg + (size_t)h * S_LEN * D_DIM;
    const float* Kh = Kg + (size_t)h * S_LEN * D_DIM;
    const float* Vh = Vg + (size_t)h * S_LEN * D_DIM;
    float*       Oh = Og + (size_t)h * S_LEN * D_DIM;

    // ---- Q fragments (B operand of swapped QK^T): lane holds Q[qrow][32ch+8g .. +8]
    const int qrow = q0 + 16 * w + q;
    bf16x8 qf[4];
    {
        const float* qp = Qh + (size_t)qrow * D_DIM;
#pragma unroll
        for (int ch = 0; ch < 4; ++ch) {
            float4 a = *(const float4*)(qp + ch * 32 + g * 8);
            float4 b = *(const float4*)(qp + ch * 32 + g * 8 + 4);
            union { uint4 u; bf16x8 v; } t;
            t.u.x = pack2(a.x, a.y); t.u.y = pack2(a.z, a.w);
            t.u.z = pack2(b.x, b.y); t.u.w = pack2(b.z, b.w);
            qf[ch] = t.v;
        }
    }

    f32x4 acc[8];
#pragma unroll
    for (int n = 0; n < 8; ++n) acc[n] = (f32x4){0.f, 0.f, 0.f, 0.f};
    float mrun = -1e30f, lrun = 0.f;

    const int klo = (qrow - WIN < 0) ? 0 : qrow - WIN;
    const int khi = qrow + WIN;    // upper bound; kk < S_LEN enforced in mask
    const int kv_base = q0 - WIN;

    for (int it = 0; it < NITER; ++it) {
        const int kv0 = kv_base + it * KVB;
        if (kv0 + KVB <= 0) continue;      // block-uniform
        if (kv0 >= S_LEN) break;           // block-uniform

        __syncthreads();
        // ---- stage K tile (bf16, swizzled): 2 passes, 16B per thread per pass
#pragma unroll
        for (int ps = 0; ps < 2; ++ps) {
            const int idx = tid + ps * 512;
            const int r = idx >> 4, c = (idx & 15) * 8;
            const int kgl = kv0 + r;
            float4 a = {0.f,0.f,0.f,0.f}, b = {0.f,0.f,0.f,0.f};
            if (kgl >= 0 && kgl < S_LEN) {
                const float* kp = Kh + (size_t)kgl * D_DIM + c;
                a = *(const float4*)kp;
                b = *(const float4*)(kp + 4);
            }
            uint4 u;
            u.x = pack2(a.x, a.y); u.y = pack2(a.z, a.w);
            u.z = pack2(b.x, b.y); u.w = pack2(b.z, b.w);
            int byte = r * 256 + c * 2;
            byte ^= (r & 7) << 4;
            *(uint4*)((char*)Klds + byte) = u;
        }
        // ---- stage V^T tile: thread -> d = tid&127, k rows 16*(tid>>7) .. +15
        {
            const int d = tid & 127, kh = tid >> 7;
            float vv[16];
#pragma unroll
            for (int bb = 0; bb < 16; ++bb) {
                const int kgl = kv0 + kh * 16 + bb;
                vv[bb] = (kgl >= 0 && kgl < S_LEN) ? Vh[(size_t)kgl * D_DIM + d] : 0.f;
            }
            uint4 u0, u1;
            u0.x = pack2(vv[0], vv[1]);  u0.y = pack2(vv[2], vv[3]);
            u0.z = pack2(vv[4], vv[5]);  u0.w = pack2(vv[6], vv[7]);
            u1.x = pack2(vv[8], vv[9]);  u1.y = pack2(vv[10], vv[11]);
            u1.z = pack2(vv[12], vv[13]); u1.w = pack2(vv[14], vv[15]);
            char* base = (char*)Vt + d * VSTRIDE + kh * 32;
            *(uint4*)base = u0;
            *(uint4*)(base + 16) = u1;
        }
        __syncthreads();

        // ---- QK^T swapped: 4 key-subtiles x 4 d-chunks
        f32x4 sa[4];
#pragma unroll
        for (int t = 0; t < 4; ++t) sa[t] = (f32x4){0.f,0.f,0.f,0.f};
#pragma unroll
        for (int ch = 0; ch < 4; ++ch) {
#pragma unroll
            for (int t = 0; t < 4; ++t) {
                const int row = t * 16 + q;
                const int byte = (row * 256 + ch * 64 + g * 16) ^ ((row & 7) << 4);
                bf16x8 kf = *(const bf16x8*)((const char*)Klds + byte);
                sa[t] = __builtin_amdgcn_mfma_f32_16x16x32_bf16(kf, qf[ch], sa[t], 0, 0, 0);
            }
        }

        // ---- masked online softmax with defer-max (THR=8)
        float p[16];
        float tmax = -1e30f;
#pragma unroll
        for (int t = 0; t < 4; ++t) {
#pragma unroll
            for (int j = 0; j < 4; ++j) {
                const int kk = kv0 + t * 16 + 4 * g + j;
                float s = sa[t][j] * scale;
                const bool v = (kk >= klo) && (kk <= khi) && (kk < S_LEN);
                s = v ? s : -1e30f;
                p[t * 4 + j] = s;
                tmax = fmaxf(tmax, s);
            }
        }
        tmax = fmaxf(tmax, __shfl_xor(tmax, 16));
        tmax = fmaxf(tmax, __shfl_xor(tmax, 32));

        if (!__all(tmax <= mrun + 8.f)) {
            const float mnew = fmaxf(mrun, tmax);
            const float alpha = __expf(mrun - mnew);
            lrun *= alpha;
            mrun = mnew;
            const float a0 = __shfl(alpha, 4 * g + 0);
            const float a1 = __shfl(alpha, 4 * g + 1);
            const float a2 = __shfl(alpha, 4 * g + 2);
            const float a3 = __shfl(alpha, 4 * g + 3);
#pragma unroll
            for (int n = 0; n < 8; ++n) {
                acc[n][0] *= a0; acc[n][1] *= a1;
                acc[n][2] *= a2; acc[n][3] *= a3;
            }
        }

        float tsum = 0.f;
#pragma unroll
        for (int i = 0; i < 16; ++i) {
            const float e = (p[i] > -1e29f) ? __expf(p[i] - mrun) : 0.f;
            p[i] = e;
            tsum += e;
        }
        tsum += __shfl_xor(tsum, 16);
        tsum += __shfl_xor(tsum, 32);
        lrun += tsum;

        // ---- P pack + redistribute: C-layout -> two A-frags (keys 0-31, 32-63)
        unsigned pk[8];
#pragma unroll
        for (int t = 0; t < 4; ++t) {
            pk[2 * t]     = pack2(p[4 * t + 0], p[4 * t + 1]);
            pk[2 * t + 1] = pack2(p[4 * t + 2], p[4 * t + 3]);
        }
        const int srcA = q + 16 * ((2 * g) & 3);
        const int srcB = q + 16 * ((2 * g + 1) & 3);
        const bool hi = (g >= 2);
        union { uint4 u; bf16x8 v; } paA, paB;
        {
            const unsigned A0 = (unsigned)__shfl((int)pk[0], srcA);
            const unsigned A1 = (unsigned)__shfl((int)pk[1], srcA);
            const unsigned A2 = (unsigned)__shfl((int)pk[2], srcA);
            const unsigned A3 = (unsigned)__shfl((int)pk[3], srcA);
            const unsigned B0 = (unsigned)__shfl((int)pk[0], srcB);
            const unsigned B1 = (unsigned)__shfl((int)pk[1], srcB);
            const unsigned B2 = (unsigned)__shfl((int)pk[2], srcB);
            const unsigned B3 = (unsigned)__shfl((int)pk[3], srcB);
            paA.u.x = hi ? A2 : A0;
            paA.u.y = hi ? A3 : A1;
            paA.u.z = hi ? B2 : B0;
            paA.u.w = hi ? B3 : B1;
        }
        {
            const unsigned A0 = (unsigned)__shfl((int)pk[4], srcA);
            const unsigned A1 = (unsigned)__shfl((int)pk[5], srcA);
            const unsigned A2 = (unsigned)__shfl((int)pk[6], srcA);
            const unsigned A3 = (unsigned)__shfl((int)pk[7], srcA);
            const unsigned B0 = (unsigned)__shfl((int)pk[4], srcB);
            const unsigned B1 = (unsigned)__shfl((int)pk[5], srcB);
            const unsigned B2 = (unsigned)__shfl((int)pk[6], srcB);
            const unsigned B3 = (unsigned)__shfl((int)pk[7], srcB);
            paB.u.x = hi ? A2 : A0;
            paB.u.y = hi ? A3 : A1;
            paB.u.z = hi ? B2 : B0;
            paB.u.w = hi ? B3 : B1;
        }

        // ---- PV: O[16q][128d] += P[16q x 64k] · V[64k x 16d] per 16-d tile
#pragma unroll
        for (int n = 0; n < 8; ++n) {
            const int row = n * 16 + q;
            const char* base = (const char*)Vt + row * VSTRIDE + g * 16;
            bf16x8 vA = *(const bf16x8*)base;
            bf16x8 vB = *(const bf16x8*)(base + 64);
            acc[n] = __builtin_amdgcn_mfma_f32_16x16x32_bf16(paA.v, vA, acc[n], 0, 0, 0);
            acc[n] = __builtin_amdgcn_mfma_f32_16x16x32_bf16(paB.v, vB, acc[n], 0, 0, 0);
        }
    }

    // ---- epilogue: normalize by lrun (lives in lane 4g+j) and store fp32
    float linv[4];
#pragma unroll
    for (int j = 0; j < 4; ++j) {
        const float lj = __shfl(lrun, 4 * g + j);
        linv[j] = 1.f / lj;
    }
#pragma unroll
    for (int n = 0; n < 8; ++n) {
#pragma unroll
        for (int j = 0; j < 4; ++j) {
            const int row = q0 + 16 * w + 4 * g + j;
            const int d = n * 16 + q;
            Oh[(size_t)row * D_DIM + d] = acc[n][j] * linv[j];
        }
    }
}

extern "C" void kernel_launch(void* const* d_in, const int* in_sizes, int n_in,
                              void* d_out, int out_size, void* d_ws, size_t ws_size,
                              hipStream_t stream) {
    const float* Q = (const float*)d_in[0];
    const float* K = (const float*)d_in[1];
    const float* V = (const float*)d_in[2];
    float* O = (float*)d_out;
    dim3 grid(S_LEN / QT, 16);   // 64 q-tiles x 16 heads
    dim3 block(512);
    hipLaunchKernelGGL(swa_fwd, grid, block, 0, stream, Q, K, V, O);
}

// Round 9
// 206.244 us; speedup vs baseline: 1.0003x; 1.0003x over previous
//
#include <hip/hip_runtime.h>
#include <hip/hip_bf16.h>

#define S_LEN 8192
#define D_DIM 128
#define WIN   256
#define QT    128
#define KVB   64
#define NITER 10            // (QT + 2*WIN) / KVB
#define VSTRIDE 144         // bytes per Vt row (72 bf16 elems)

typedef __attribute__((ext_vector_type(8))) short bf16x8;
typedef __attribute__((ext_vector_type(4))) float f32x4;

__device__ inline unsigned pack2(float lo, float hi) {
    __hip_bfloat162 h = __float22bfloat162_rn(make_float2(lo, hi));  // v_cvt_pk_bf16_f32
    unsigned r; __builtin_memcpy(&r, &h, 4); return r;
}

// (512, 4): 4 waves/EU min -> 2 blocks/CU -> 128-VGPR budget. Round-8's default
// budget (64 VGPR) starved the 16-load V staging and serialized it (VGPR=60, idle-bound).
__global__ __launch_bounds__(512, 4)
void swa_fwd(const float* __restrict__ Qg, const float* __restrict__ Kg,
             const float* __restrict__ Vg, float* __restrict__ Og) {
    // K tile: row-major [64][128] bf16, XOR-swizzled (byte ^= (row&7)<<4)
    __shared__ __align__(16) unsigned short Klds[KVB * D_DIM];
    // V^T tile: [d=128][k=64] bf16, row stride 72 elems (144 B) -> conflict-free phases
    __shared__ __align__(16) unsigned short Vt[D_DIM * (VSTRIDE / 2)];

    const int tid = threadIdx.x;
    const int l = tid & 63;
    const int w = tid >> 6;        // wave 0..7, each owns 16 q-rows
    const int q = l & 15;
    const int g = l >> 4;
    const int h = blockIdx.y;
    const int q0 = blockIdx.x * QT;
    const float scale = 0.08838834764831845f;  // 1/sqrt(128)

    const float* Qh = Qg + (size_t)h * S_LEN * D_DIM;
    const float* Kh = Kg + (size_t)h * S_LEN * D_DIM;
    const float* Vh = Vg + (size_t)h * S_LEN * D_DIM;
    float*       Oh = Og + (size_t)h * S_LEN * D_DIM;

    // ---- Q fragments (B operand of swapped QK^T): lane holds Q[qrow][32ch+8g .. +8]
    const int qrow = q0 + 16 * w + q;
    bf16x8 qf[4];
    {
        const float* qp = Qh + (size_t)qrow * D_DIM;
#pragma unroll
        for (int ch = 0; ch < 4; ++ch) {
            float4 a = *(const float4*)(qp + ch * 32 + g * 8);
            float4 b = *(const float4*)(qp + ch * 32 + g * 8 + 4);
            union { uint4 u; bf16x8 v; } t;
            t.u.x = pack2(a.x, a.y); t.u.y = pack2(a.z, a.w);
            t.u.z = pack2(b.x, b.y); t.u.w = pack2(b.z, b.w);
            qf[ch] = t.v;
        }
    }

    f32x4 acc[8];
#pragma unroll
    for (int n = 0; n < 8; ++n) acc[n] = (f32x4){0.f, 0.f, 0.f, 0.f};
    float mrun = -1e30f, lrun = 0.f;

    const int klo = (qrow - WIN < 0) ? 0 : qrow - WIN;
    const int khi = qrow + WIN;    // upper bound; kk < S_LEN enforced in mask
    const int kv_base = q0 - WIN;

    for (int it = 0; it < NITER; ++it) {
        const int kv0 = kv_base + it * KVB;
        if (kv0 + KVB <= 0) continue;      // block-uniform
        if (kv0 >= S_LEN) break;           // block-uniform

        __syncthreads();
        // ---- stage K tile (bf16, swizzled): 2 passes, 16B per thread per pass
#pragma unroll
        for (int ps = 0; ps < 2; ++ps) {
            const int idx = tid + ps * 512;
            const int r = idx >> 4, c = (idx & 15) * 8;
            const int kgl = kv0 + r;
            float4 a = {0.f,0.f,0.f,0.f}, b = {0.f,0.f,0.f,0.f};
            if (kgl >= 0 && kgl < S_LEN) {
                const float* kp = Kh + (size_t)kgl * D_DIM + c;
                a = *(const float4*)kp;
                b = *(const float4*)(kp + 4);
            }
            uint4 u;
            u.x = pack2(a.x, a.y); u.y = pack2(a.z, a.w);
            u.z = pack2(b.x, b.y); u.w = pack2(b.z, b.w);
            int byte = r * 256 + c * 2;
            byte ^= (r & 7) << 4;
            *(uint4*)((char*)Klds + byte) = u;
        }
        // ---- stage V^T tile: thread -> d = tid&127, k rows 16*(tid>>7) .. +15
        {
            const int d = tid & 127, kh = tid >> 7;
            float vv[16];
#pragma unroll
            for (int bb = 0; bb < 16; ++bb) {
                const int kgl = kv0 + kh * 16 + bb;
                vv[bb] = (kgl >= 0 && kgl < S_LEN) ? Vh[(size_t)kgl * D_DIM + d] : 0.f;
            }
            uint4 u0, u1;
            u0.x = pack2(vv[0], vv[1]);  u0.y = pack2(vv[2], vv[3]);
            u0.z = pack2(vv[4], vv[5]);  u0.w = pack2(vv[6], vv[7]);
            u1.x = pack2(vv[8], vv[9]);  u1.y = pack2(vv[10], vv[11]);
            u1.z = pack2(vv[12], vv[13]); u1.w = pack2(vv[14], vv[15]);
            char* base = (char*)Vt + d * VSTRIDE + kh * 32;
            *(uint4*)base = u0;
            *(uint4*)(base + 16) = u1;
        }
        __syncthreads();

        // ---- QK^T swapped: 4 key-subtiles x 4 d-chunks
        f32x4 sa[4];
#pragma unroll
        for (int t = 0; t < 4; ++t) sa[t] = (f32x4){0.f,0.f,0.f,0.f};
#pragma unroll
        for (int ch = 0; ch < 4; ++ch) {
#pragma unroll
            for (int t = 0; t < 4; ++t) {
                const int row = t * 16 + q;
                const int byte = (row * 256 + ch * 64 + g * 16) ^ ((row & 7) << 4);
                bf16x8 kf = *(const bf16x8*)((const char*)Klds + byte);
                sa[t] = __builtin_amdgcn_mfma_f32_16x16x32_bf16(kf, qf[ch], sa[t], 0, 0, 0);
            }
        }

        // ---- masked online softmax with defer-max (THR=8)
        float p[16];
        float tmax = -1e30f;
#pragma unroll
        for (int t = 0; t < 4; ++t) {
#pragma unroll
            for (int j = 0; j < 4; ++j) {
                const int kk = kv0 + t * 16 + 4 * g + j;
                float s = sa[t][j] * scale;
                const bool v = (kk >= klo) && (kk <= khi) && (kk < S_LEN);
                s = v ? s : -1e30f;
                p[t * 4 + j] = s;
                tmax = fmaxf(tmax, s);
            }
        }
        tmax = fmaxf(tmax, __shfl_xor(tmax, 16));
        tmax = fmaxf(tmax, __shfl_xor(tmax, 32));

        if (!__all(tmax <= mrun + 8.f)) {
            const float mnew = fmaxf(mrun, tmax);
            const float alpha = __expf(mrun - mnew);
            lrun *= alpha;
            mrun = mnew;
            const float a0 = __shfl(alpha, 4 * g + 0);
            const float a1 = __shfl(alpha, 4 * g + 1);
            const float a2 = __shfl(alpha, 4 * g + 2);
            const float a3 = __shfl(alpha, 4 * g + 3);
#pragma unroll
            for (int n = 0; n < 8; ++n) {
                acc[n][0] *= a0; acc[n][1] *= a1;
                acc[n][2] *= a2; acc[n][3] *= a3;
            }
        }

        float tsum = 0.f;
#pragma unroll
        for (int i = 0; i < 16; ++i) {
            const float e = (p[i] > -1e29f) ? __expf(p[i] - mrun) : 0.f;
            p[i] = e;
            tsum += e;
        }
        tsum += __shfl_xor(tsum, 16);
        tsum += __shfl_xor(tsum, 32);
        lrun += tsum;

        // ---- P pack + redistribute: C-layout -> two A-frags (keys 0-31, 32-63)
        unsigned pk[8];
#pragma unroll
        for (int t = 0; t < 4; ++t) {
            pk[2 * t]     = pack2(p[4 * t + 0], p[4 * t + 1]);
            pk[2 * t + 1] = pack2(p[4 * t + 2], p[4 * t + 3]);
        }
        const int srcA = q + 16 * ((2 * g) & 3);
        const int srcB = q + 16 * ((2 * g + 1) & 3);
        const bool hi = (g >= 2);
        union { uint4 u; bf16x8 v; } paA, paB;
        {
            const unsigned A0 = (unsigned)__shfl((int)pk[0], srcA);
            const unsigned A1 = (unsigned)__shfl((int)pk[1], srcA);
            const unsigned A2 = (unsigned)__shfl((int)pk[2], srcA);
            const unsigned A3 = (unsigned)__shfl((int)pk[3], srcA);
            const unsigned B0 = (unsigned)__shfl((int)pk[0], srcB);
            const unsigned B1 = (unsigned)__shfl((int)pk[1], srcB);
            const unsigned B2 = (unsigned)__shfl((int)pk[2], srcB);
            const unsigned B3 = (unsigned)__shfl((int)pk[3], srcB);
            paA.u.x = hi ? A2 : A0;
            paA.u.y = hi ? A3 : A1;
            paA.u.z = hi ? B2 : B0;
            paA.u.w = hi ? B3 : B1;
        }
        {
            const unsigned A0 = (unsigned)__shfl((int)pk[4], srcA);
            const unsigned A1 = (unsigned)__shfl((int)pk[5], srcA);
            const unsigned A2 = (unsigned)__shfl((int)pk[6], srcA);
            const unsigned A3 = (unsigned)__shfl((int)pk[7], srcA);
            const unsigned B0 = (unsigned)__shfl((int)pk[4], srcB);
            const unsigned B1 = (unsigned)__shfl((int)pk[5], srcB);
            const unsigned B2 = (unsigned)__shfl((int)pk[6], srcB);
            const unsigned B3 = (unsigned)__shfl((int)pk[7], srcB);
            paB.u.x = hi ? A2 : A0;
            paB.u.y = hi ? A3 : A1;
            paB.u.z = hi ? B2 : B0;
            paB.u.w = hi ? B3 : B1;
        }

        // ---- PV: O[16q][128d] += P[16q x 64k] · V[64k x 16d] per 16-d tile
#pragma unroll
        for (int n = 0; n < 8; ++n) {
            const int row = n * 16 + q;
            const char* base = (const char*)Vt + row * VSTRIDE + g * 16;
            bf16x8 vA = *(const bf16x8*)base;
            bf16x8 vB = *(const bf16x8*)(base + 64);
            acc[n] = __builtin_amdgcn_mfma_f32_16x16x32_bf16(paA.v, vA, acc[n], 0, 0, 0);
            acc[n] = __builtin_amdgcn_mfma_f32_16x16x32_bf16(paB.v, vB, acc[n], 0, 0, 0);
        }
    }

    // ---- epilogue: normalize by lrun (lives in lane 4g+j) and store fp32
    float linv[4];
#pragma unroll
    for (int j = 0; j < 4; ++j) {
        const float lj = __shfl(lrun, 4 * g + j);
        linv[j] = 1.f / lj;
    }
#pragma unroll
    for (int n = 0; n < 8; ++n) {
#pragma unroll
        for (int j = 0; j < 4; ++j) {
            const int row = q0 + 16 * w + 4 * g + j;
            const int d = n * 16 + q;
            Oh[(size_t)row * D_DIM + d] = acc[n][j] * linv[j];
        }
    }
}

extern "C" void kernel_launch(void* const* d_in, const int* in_sizes, int n_in,
                              void* d_out, int out_size, void* d_ws, size_t ws_size,
                              hipStream_t stream) {
    const float* Q = (const float*)d_in[0];
    const float* K = (const float*)d_in[1];
    const float* V = (const float*)d_in[2];
    float* O = (float*)d_out;
    dim3 grid(S_LEN / QT, 16);   // 64 q-tiles x 16 heads
    dim3 block(512);
    hipLaunchKernelGGL(swa_fwd, grid, block, 0, stream, Q, K, V, O);
}